// Round 9
// baseline (112.843 us; speedup 1.0000x reference)
//
#include <hip/hip_runtime.h>
#include <hip/hip_bf16.h>
#include <stdint.h>

#define B_SZ 16384
#define D_SZ 512
#define N_SZ 1024

using f16x8 = __attribute__((ext_vector_type(8))) _Float16;
using f32x4 = __attribute__((ext_vector_type(4))) float;

__device__ __forceinline__ unsigned short f16bits(_Float16 h) {
    return __builtin_bit_cast(unsigned short, h);
}

// ---- merged prep (unchanged from R8, proven) ----
__global__ __launch_bounds__(256) void prep(
    const float* __restrict__ W, const float* __restrict__ X,
    _Float16* __restrict__ wh, _Float16* __restrict__ wt,
    float* __restrict__ ww, _Float16* __restrict__ xh) {
    const int bid = blockIdx.x;
    const int t = threadIdx.x;
    if (bid < 32) {
        __shared__ unsigned int cells[512 * 17];
        const int n0 = bid * 32;
        const int np = t >> 4;
        const int dc = t & 15;
        const int na = n0 + 2 * np, nb = na + 1;
        const int d0 = dc * 32;
        float va[32], vb[32];
#pragma unroll
        for (int i = 0; i < 8; ++i) {
            *reinterpret_cast<float4*>(&va[i * 4]) =
                *reinterpret_cast<const float4*>(&W[(size_t)na * D_SZ + d0 + i * 4]);
            *reinterpret_cast<float4*>(&vb[i * 4]) =
                *reinterpret_cast<const float4*>(&W[(size_t)nb * D_SZ + d0 + i * 4]);
        }
        float sa = 0.f, sb = 0.f;
#pragma unroll
        for (int i = 0; i < 32; ++i) { sa += va[i] * va[i]; sb += vb[i] * vb[i]; }
        sa += __shfl_xor(sa, 1); sa += __shfl_xor(sa, 2);
        sa += __shfl_xor(sa, 4); sa += __shfl_xor(sa, 8);
        sb += __shfl_xor(sb, 1); sb += __shfl_xor(sb, 2);
        sb += __shfl_xor(sb, 4); sb += __shfl_xor(sb, 8);
        if (dc == 0) { ww[na] = sa; ww[nb] = sb; }
        _Float16 ha[32], hb[32];
#pragma unroll
        for (int i = 0; i < 32; ++i) { ha[i] = (_Float16)va[i]; hb[i] = (_Float16)vb[i]; }
        unsigned int pa[16], pb[16];
#pragma unroll
        for (int j = 0; j < 16; ++j) {
            pa[j] = (unsigned)f16bits(ha[2 * j]) | ((unsigned)f16bits(ha[2 * j + 1]) << 16);
            pb[j] = (unsigned)f16bits(hb[2 * j]) | ((unsigned)f16bits(hb[2 * j + 1]) << 16);
        }
        unsigned int* whU = reinterpret_cast<unsigned int*>(wh);
#pragma unroll
        for (int j = 0; j < 4; ++j) {
            *reinterpret_cast<uint4*>(&whU[((size_t)na * D_SZ + d0) / 2 + j * 4]) =
                make_uint4(pa[j * 4], pa[j * 4 + 1], pa[j * 4 + 2], pa[j * 4 + 3]);
            *reinterpret_cast<uint4*>(&whU[((size_t)nb * D_SZ + d0) / 2 + j * 4]) =
                make_uint4(pb[j * 4], pb[j * 4 + 1], pb[j * 4 + 2], pb[j * 4 + 3]);
        }
#pragma unroll
        for (int k = 0; k < 32; ++k) {
            const int d = d0 + k;
            const unsigned u = (unsigned)f16bits(ha[k]) | ((unsigned)f16bits(hb[k]) << 16);
            cells[d * 17 + (np ^ ((d >> 5) & 15))] = u;
        }
        __syncthreads();
        for (int rr = 0; rr < 2; ++rr) {
            const int d = 2 * t + rr;
            const int px = (d >> 5) & 15;
            unsigned int buf[16];
#pragma unroll
            for (int j = 0; j < 16; ++j) buf[j] = cells[d * 17 + (j ^ px)];
            unsigned int* wtU = reinterpret_cast<unsigned int*>(wt);
#pragma unroll
            for (int j = 0; j < 4; ++j)
                *reinterpret_cast<uint4*>(&wtU[((size_t)d * N_SZ + n0) / 2 + j * 4]) =
                    make_uint4(buf[j * 4], buf[j * 4 + 1], buf[j * 4 + 2], buf[j * 4 + 3]);
        }
    } else {
        const int b2 = bid - 32;
        const int chunk = (b2 & 7) * 512 + (b2 >> 3);
        const size_t idx = ((size_t)chunk * 256 + t) * 8;
        const float4 a = *reinterpret_cast<const float4*>(&X[idx]);
        const float4 b = *reinterpret_cast<const float4*>(&X[idx + 4]);
        f16x8 h = {(_Float16)a.x, (_Float16)a.y, (_Float16)a.z, (_Float16)a.w,
                   (_Float16)b.x, (_Float16)b.y, (_Float16)b.z, (_Float16)b.w};
        *reinterpret_cast<f16x8*>(&xh[idx]) = h;
    }
}

// ---- fused: gemm1 (64x1024) + dual-axis softmax + gemm2 (64x512) ----
// Block: 512 threads / 8 waves; wave w owns n-slice [128w,128w+128) in phase 1
// and d-slice [64w,64w+64) in phase 3. All W/Wt fragments direct-from-global
// (L2-resident); LDS only for softmax reductions + swizzled a-tile.
__global__ __launch_bounds__(512, 2) void fused(
    const _Float16* __restrict__ xh, const _Float16* __restrict__ wh,
    const _Float16* __restrict__ wt, const float* __restrict__ ww,
    float* __restrict__ Y) {
    __shared__ __align__(16) char lds[152064];
    float* csw = (float*)lds;                  // [8][64][32] partials (dead before Ltile)
    float* rs  = (float*)(lds + 131072);       // [64][32]
    float* Mx  = (float*)(lds + 139264);       // [64][8]
    float* Tw  = (float*)(lds + 141312);       // [64][8]
    float* Mv  = (float*)(lds + 143360);       // [64]
    float* Tv  = (float*)(lds + 143616);       // [64]
    float* csf = (float*)(lds + 143872);       // [64][32]

    const int tid = threadIdx.x;
    const int w = tid >> 6, l = tid & 63;
    const int l4 = l >> 4, lm = l & 15;
    const int raw = blockIdx.x;                       // 0..255
    const int bm0 = ((raw & 7) * 32 + (raw >> 3)) * 64;  // XCD-chunked

    // ================= phase 1: logits =================
    f32x4 acc[4][8];
#pragma unroll
    for (int mi = 0; mi < 4; ++mi)
#pragma unroll
        for (int ni = 0; ni < 8; ++ni) acc[mi][ni] = (f32x4){0.f, 0.f, 0.f, 0.f};

    for (int kt = 0; kt < 16; ++kt) {
        const int gk = kt * 32;
        f16x8 af[4], bf[8];
#pragma unroll
        for (int mi = 0; mi < 4; ++mi)
            af[mi] = *reinterpret_cast<const f16x8*>(
                &xh[(size_t)(bm0 + mi * 16 + lm) * D_SZ + gk + l4 * 8]);
#pragma unroll
        for (int ni = 0; ni < 8; ++ni)
            bf[ni] = *reinterpret_cast<const f16x8*>(
                &wh[(size_t)(w * 128 + ni * 16 + lm) * D_SZ + gk + l4 * 8]);
#pragma unroll
        for (int mi = 0; mi < 4; ++mi)
#pragma unroll
            for (int ni = 0; ni < 8; ++ni)
                acc[mi][ni] = __builtin_amdgcn_mfma_f32_16x16x32_f16(af[mi], bf[ni], acc[mi][ni], 0, 0, 0);
    }
    // logits = 4*dot - 2*||w||^2
    float wwv[8];
#pragma unroll
    for (int ni = 0; ni < 8; ++ni) wwv[ni] = ww[w * 128 + ni * 16 + lm];
#pragma unroll
    for (int mi = 0; mi < 4; ++mi)
#pragma unroll
        for (int ni = 0; ni < 8; ++ni)
#pragma unroll
            for (int r = 0; r < 4; ++r)
                acc[mi][ni][r] = 4.f * acc[mi][ni][r] - 2.f * wwv[ni];

    // ================= phase 2: dual-axis softmax =================
    // Step A: global per-row max
#pragma unroll
    for (int mi = 0; mi < 4; ++mi)
#pragma unroll
        for (int r = 0; r < 4; ++r) {
            float m = acc[mi][0][r];
#pragma unroll
            for (int ni = 1; ni < 8; ++ni) m = fmaxf(m, acc[mi][ni][r]);
            m = fmaxf(m, __shfl_xor(m, 1));
            m = fmaxf(m, __shfl_xor(m, 2));
            m = fmaxf(m, __shfl_xor(m, 4));
            m = fmaxf(m, __shfl_xor(m, 8));
            if (lm == 0) Mx[(mi * 16 + l4 * 4 + r) * 8 + w] = m;
        }
    __syncthreads();
    if (tid < 64) {
        float m = Mx[tid * 8];
#pragma unroll
        for (int k = 1; k < 8; ++k) m = fmaxf(m, Mx[tid * 8 + k]);
        Mv[tid] = m;
    }
    __syncthreads();
    // Step B: u = exp(l - M); row sums rs[b][i]; col partials csw[w][b][j]
#pragma unroll
    for (int mi = 0; mi < 4; ++mi)
#pragma unroll
        for (int r = 0; r < 4; ++r) {
            const int b = mi * 16 + l4 * 4 + r;
            const float Mb = Mv[b];
            float u[8];
#pragma unroll
            for (int ni = 0; ni < 8; ++ni) {
                u[ni] = __expf(acc[mi][ni][r] - Mb);
                acc[mi][ni][r] = u[ni];
            }
#pragma unroll
            for (int ip = 0; ip < 4; ++ip) {
                float s = u[2 * ip] + u[2 * ip + 1];
                s += __shfl_xor(s, 1); s += __shfl_xor(s, 2);
                s += __shfl_xor(s, 4); s += __shfl_xor(s, 8);
                if (lm == 0) rs[b * 32 + 4 * w + ip] = s;
            }
#pragma unroll
            for (int jp = 0; jp < 2; ++jp) {
                const float c = (u[jp] + u[2 + jp]) + (u[4 + jp] + u[6 + jp]);
                csw[(w * 64 + b) * 32 + jp * 16 + lm] = c;
            }
        }
    __syncthreads();
    for (int c = tid; c < 2048; c += 512) {
        float s = csw[c];
#pragma unroll
        for (int k = 1; k < 8; ++k) s += csw[k * 2048 + c];
        csf[c] = s;
    }
    __syncthreads();
    // Step C: t = u^2/(rs*cs); T[b] = sum t
#pragma unroll
    for (int mi = 0; mi < 4; ++mi)
#pragma unroll
        for (int r = 0; r < 4; ++r) {
            const int b = mi * 16 + l4 * 4 + r;
            float rsv[4], csv[2];
#pragma unroll
            for (int ip = 0; ip < 4; ++ip) rsv[ip] = __builtin_amdgcn_rcpf(rs[b * 32 + 4 * w + ip]);
#pragma unroll
            for (int jp = 0; jp < 2; ++jp) csv[jp] = __builtin_amdgcn_rcpf(csf[b * 32 + jp * 16 + lm]);
            float tsum = 0.f;
#pragma unroll
            for (int ni = 0; ni < 8; ++ni) {
                const float uu = acc[mi][ni][r];
                const float t = uu * uu * rsv[ni >> 1] * csv[ni & 1];
                acc[mi][ni][r] = t;
                tsum += t;
            }
            tsum += __shfl_xor(tsum, 1); tsum += __shfl_xor(tsum, 2);
            tsum += __shfl_xor(tsum, 4); tsum += __shfl_xor(tsum, 8);
            if (lm == 0) Tw[b * 8 + w] = tsum;
        }
    __syncthreads();
    if (tid < 64) {
        float s = Tw[tid * 8];
#pragma unroll
        for (int k = 1; k < 8; ++k) s += Tw[tid * 8 + k];
        Tv[tid] = __builtin_amdgcn_rcpf(s + 1e-8f);
    }
    __syncthreads();
    // Step D: a -> swizzled Ltile [64][1024] f16 (overwrites csw region)
#pragma unroll
    for (int mi = 0; mi < 4; ++mi)
#pragma unroll
        for (int r = 0; r < 4; ++r) {
            const int b = mi * 16 + l4 * 4 + r;
            const float Tb = Tv[b];
#pragma unroll
            for (int ni = 0; ni < 8; ++ni) {
                const int n = w * 128 + ni * 16 + lm;
                const int off = b * 2048 + ((n * 2) ^ ((b & 7) << 4));
                *reinterpret_cast<_Float16*>(lds + off) = (_Float16)(acc[mi][ni][r] * Tb);
            }
        }
    __syncthreads();

    // ================= phase 3: y = a @ W =================
    f32x4 acc2[4][4];
#pragma unroll
    for (int mi = 0; mi < 4; ++mi)
#pragma unroll
        for (int di = 0; di < 4; ++di) acc2[mi][di] = (f32x4){0.f, 0.f, 0.f, 0.f};

    for (int kt = 0; kt < 32; ++kt) {
        f16x8 a4[4], b4[4];
#pragma unroll
        for (int mi = 0; mi < 4; ++mi) {
            const int b = mi * 16 + lm;
            const int off = b * 2048 + ((kt * 64 + l4 * 16) ^ ((b & 7) << 4));
            a4[mi] = *reinterpret_cast<const f16x8*>(lds + off);
        }
#pragma unroll
        for (int di = 0; di < 4; ++di) {
            const int d = w * 64 + di * 16 + lm;
            b4[di] = *reinterpret_cast<const f16x8*>(
                &wt[(size_t)d * N_SZ + kt * 32 + l4 * 8]);
        }
#pragma unroll
        for (int mi = 0; mi < 4; ++mi)
#pragma unroll
            for (int di = 0; di < 4; ++di)
                acc2[mi][di] = __builtin_amdgcn_mfma_f32_16x16x32_f16(a4[mi], b4[di], acc2[mi][di], 0, 0, 0);
    }
#pragma unroll
    for (int mi = 0; mi < 4; ++mi)
#pragma unroll
        for (int di = 0; di < 4; ++di) {
            const int dd = w * 64 + di * 16 + lm;
            const int bb = bm0 + mi * 16 + l4 * 4;
#pragma unroll
            for (int r = 0; r < 4; ++r)
                Y[(size_t)(bb + r) * D_SZ + dd] = acc2[mi][di][r];
        }
}

extern "C" void kernel_launch(void* const* d_in, const int* in_sizes, int n_in,
                              void* d_out, int out_size, void* d_ws, size_t ws_size,
                              hipStream_t stream) {
    (void)in_sizes; (void)n_in; (void)out_size; (void)ws_size;
    const float* X = (const float*)d_in[0];
    const float* W = (const float*)d_in[1];
    float* Y = (float*)d_out;
    char* ws = (char*)d_ws;

    // Workspace: wh 1M | wt 1M | ww 4K | xh 16M  (~18 MiB)
    _Float16* wh = (_Float16*)ws;
    _Float16* wt = (_Float16*)(ws + (size_t)1 * 1024 * 1024);
    float*    ww = (float*)   (ws + (size_t)2 * 1024 * 1024);
    _Float16* xh = (_Float16*)(ws + (size_t)2 * 1024 * 1024 + 4096);

    prep<<<32 + 4096, 256, 0, stream>>>(W, X, wh, wt, ww, xh);
    fused<<<256, 512, 0, stream>>>(xh, wh, wt, ww, Y);
}